// Round 2
// baseline (124.283 us; speedup 1.0000x reference)
//
#include <hip/hip_runtime.h>

#define EPS 1e-3f
#define Bn 16
#define Tn 2048
#define Dn 256
#define Kn 8
#define TS 128           // t-chunks per batch row
#define TCH (Tn / TS)    // 16 t per block

__device__ __forceinline__ float fexp2(float x) {
#if __has_builtin(__builtin_amdgcn_exp2f)
    return __builtin_amdgcn_exp2f(x);
#else
    return exp2f(x);
#endif
}

__device__ __forceinline__ float frcp(float x) {
#if __has_builtin(__builtin_amdgcn_rcpf)
    return __builtin_amdgcn_rcpf(x);
#else
    return 1.0f / x;
#endif
}

// Tiny: per (k,d) quadratic-in-x exponent coefficients.
// exp(-0.5 (x-m)^2 / (sp+eps)) = exp2(A x^2 + B x + G)
__global__ __launch_bounds__(256) void ucb_coef(
    const float* __restrict__ Mean, const float* __restrict__ Var,
    float* __restrict__ CA, float* __restrict__ CB, float* __restrict__ CG)
{
    int i = blockIdx.x * 256 + threadIdx.x;       // over K*D = 2048
    const float L2E = 1.4426950408889634f;
    float m  = Mean[i];
    float v  = Var[i];
    float sp = logf(1.0f + expf(v));              // softplus
    float c2 = -0.5f * L2E / (sp + EPS);
    CA[i] = c2;
    CB[i] = -2.0f * c2 * m;
    CG[i] = c2 * m * m;
}

// Pass 1: S0[k,b,d] += sum_t tau ; A1[k,b,d] += sum_t tau*x ;
//         A3[k,b,d] += sum_t tau^3*x^2
__global__ __launch_bounds__(256) void ucb_pass1(
    const float* __restrict__ X,
    const float* __restrict__ CA, const float* __restrict__ CB,
    const float* __restrict__ CG,
    float* __restrict__ S0, float* __restrict__ A1, float* __restrict__ A3)
{
    const int d  = threadIdx.x;          // 0..255 (= Dn)
    const int tc = blockIdx.x;           // t-chunk
    const int b  = blockIdx.y;           // batch

    float Ak[Kn], Bk[Kn], Gk[Kn];
#pragma unroll
    for (int k = 0; k < Kn; ++k) {
        Ak[k] = CA[k * Dn + d];
        Bk[k] = CB[k * Dn + d];
        Gk[k] = CG[k * Dn + d];
    }

    float s0[Kn], s1[Kn], s3[Kn];
#pragma unroll
    for (int k = 0; k < Kn; ++k) { s0[k] = 0.f; s1[k] = 0.f; s3[k] = 0.f; }

    const float* xp = X + ((size_t)b * Tn + (size_t)tc * TCH) * Dn + d;
#pragma unroll 4
    for (int t = 0; t < TCH; ++t) {
        float x = xp[(size_t)t * Dn];
        float p[Kn];
        float sum = EPS;
#pragma unroll
        for (int k = 0; k < Kn; ++k) {
            float arg = fmaf(fmaf(Ak[k], x, Bk[k]), x, Gk[k]);
            p[k] = fexp2(arg);
            sum += p[k];
        }
        float inv = frcp(sum);
        float xx  = x * x;
#pragma unroll
        for (int k = 0; k < Kn; ++k) {
            float tau = p[k] * inv;
            s0[k] += tau;
            s1[k]  = fmaf(tau, x, s1[k]);
            float t3 = tau * tau * tau;
            s3[k]  = fmaf(t3, xx, s3[k]);
        }
    }

#pragma unroll
    for (int k = 0; k < Kn; ++k) {
        size_t idx = ((size_t)k * Bn + b) * Dn + d;
        atomicAdd(&S0[idx], s0[k]);
        atomicAdd(&A1[idx], s1[k]);
        atomicAdd(&A3[idx], s3[k]);
    }
}

// Mid: per (k,b,d) -> R = rs / sqrt(V+eps), RE = R*E
__global__ __launch_bounds__(256) void ucb_mid(
    const float* __restrict__ S0, const float* __restrict__ A1,
    const float* __restrict__ A3,
    float* __restrict__ R, float* __restrict__ RE)
{
    int idx = blockIdx.x * 256 + threadIdx.x;  // over K*B*D, ordered (k,b,d)
    int k = idx >> 12;                          // / (Bn*Dn)
    int d = idx & (Dn - 1);

    float s = EPS;
#pragma unroll
    for (int b2 = 0; b2 < Bn; ++b2)
        s += S0[((size_t)k * Bn + b2) * Dn + d];
    float iS = 1.0f / s;

    const float rs = rsqrtf(1.0f + EPS);        // 1/sqrt(pri+eps), pri==1
    float a1 = A1[idx];
    float a3 = A3[idx];
    float E  = a1 * iS * (1.0f / Tn);
    float V  = a3 * iS * iS * iS * (1.0f / Tn);
    float r  = rs * rsqrtf(V + EPS);
    R[idx]  = r;
    RE[idx] = r * E;
}

// Pass 2: out = (1/(sum_p+eps)) * sum_k p_k * (Rk*x - REk)
__global__ __launch_bounds__(256) void ucb_pass2(
    const float* __restrict__ X,
    const float* __restrict__ CA, const float* __restrict__ CB,
    const float* __restrict__ CG,
    const float* __restrict__ R, const float* __restrict__ RE,
    float* __restrict__ Out)
{
    const int d  = threadIdx.x;
    const int tc = blockIdx.x;
    const int b  = blockIdx.y;

    float Ak[Kn], Bk[Kn], Gk[Kn], Rk[Kn], REk[Kn];
#pragma unroll
    for (int k = 0; k < Kn; ++k) {
        Ak[k] = CA[k * Dn + d];
        Bk[k] = CB[k * Dn + d];
        Gk[k] = CG[k * Dn + d];
        size_t idx = ((size_t)k * Bn + b) * Dn + d;
        Rk[k]  = R[idx];
        REk[k] = RE[idx];
    }

    const size_t base = ((size_t)b * Tn + (size_t)tc * TCH) * Dn + d;
#pragma unroll 4
    for (int t = 0; t < TCH; ++t) {
        float x = X[base + (size_t)t * Dn];
        float p[Kn];
        float sum = EPS;
#pragma unroll
        for (int k = 0; k < Kn; ++k) {
            float arg = fmaf(fmaf(Ak[k], x, Bk[k]), x, Gk[k]);
            p[k] = fexp2(arg);
            sum += p[k];
        }
        float inv = frcp(sum);
        float acc = 0.f;
#pragma unroll
        for (int k = 0; k < Kn; ++k) {
            acc = fmaf(p[k], fmaf(Rk[k], x, -REk[k]), acc);
        }
        Out[base + (size_t)t * Dn] = acc * inv;
    }
}

extern "C" void kernel_launch(void* const* d_in, const int* in_sizes, int n_in,
                              void* d_out, int out_size, void* d_ws, size_t ws_size,
                              hipStream_t stream)
{
    const float* x    = (const float*)d_in[0];
    const float* mean = (const float*)d_in[1];
    const float* var  = (const float*)d_in[2];
    // d_in[3] (prior): softmax over singleton axis == 1 -> only enters as
    // the compile-time constant rsqrt(1+eps).

    const size_t KBD = (size_t)Kn * Bn * Dn;   // 32768
    const size_t KD  = (size_t)Kn * Dn;        // 2048

    float* S0 = (float*)d_ws;            // KBD  (atomic targets first, contiguous)
    float* A1 = S0 + KBD;                // KBD
    float* A3 = A1 + KBD;                // KBD
    float* CA = A3 + KBD;                // KD
    float* CB = CA + KD;                 // KD
    float* CG = CB + KD;                 // KD
    float* R  = CG + KD;                 // KBD
    float* RE = R  + KBD;                // KBD

    hipMemsetAsync(d_ws, 0, 3 * KBD * sizeof(float), stream);

    ucb_coef<<<dim3(KD / 256), dim3(256), 0, stream>>>(mean, var, CA, CB, CG);

    dim3 grid(TS, Bn), block(256);
    ucb_pass1<<<grid, block, 0, stream>>>(x, CA, CB, CG, S0, A1, A3);

    ucb_mid<<<dim3(KBD / 256), dim3(256), 0, stream>>>(S0, A1, A3, R, RE);

    ucb_pass2<<<grid, block, 0, stream>>>(x, CA, CB, CG, R, RE, (float*)d_out);
}

// Round 3
// 60.101 us; speedup vs baseline: 2.0679x; 2.0679x over previous
//
#include <hip/hip_runtime.h>

#define EPS 1e-3f
#define Bn 16
#define Tn 2048
#define Dn 256
#define Kn 8
#define TS2 128          // t-chunks per batch row for pass2
#define TCH2 (Tn / TS2)  // 16

#define KBD ((size_t)Kn * Bn * Dn)   // 32768
#define KD  ((size_t)Kn * Dn)        // 2048

__device__ __forceinline__ float fexp2(float x) {
#if __has_builtin(__builtin_amdgcn_exp2f)
    return __builtin_amdgcn_exp2f(x);
#else
    return exp2f(x);
#endif
}

__device__ __forceinline__ float frcp(float x) {
#if __has_builtin(__builtin_amdgcn_rcpf)
    return __builtin_amdgcn_rcpf(x);
#else
    return 1.0f / x;
#endif
}

// exp(-0.5 (x-m)^2 / (softplus(v)+eps)) = exp2(A x^2 + B x + G)
__global__ __launch_bounds__(256) void ucb_coef(
    const float* __restrict__ Mean, const float* __restrict__ Var,
    float* __restrict__ CA, float* __restrict__ CB, float* __restrict__ CG)
{
    int i = blockIdx.x * 256 + threadIdx.x;       // over K*D = 2048
    const float L2E = 1.4426950408889634f;
    float m  = Mean[i];
    float v  = Var[i];
    float sp = logf(1.0f + expf(v));              // softplus
    float c2 = -0.5f * L2E / (sp + EPS);
    CA[i] = c2;
    CB[i] = -2.0f * c2 * m;
    CG[i] = c2 * m * m;
}

// Pass 1: per-block partials (no atomics):
//   P0[tc,k,b,d] = sum_t tau ; P1 = sum_t tau*x ; P3 = sum_t tau^3*x^2
__global__ __launch_bounds__(256) void ucb_pass1(
    const float* __restrict__ X,
    const float* __restrict__ CA, const float* __restrict__ CB,
    const float* __restrict__ CG,
    float* __restrict__ P0, float* __restrict__ P1, float* __restrict__ P3,
    int tch)
{
    const int d  = threadIdx.x;          // 0..255 (= Dn)
    const int tc = blockIdx.x;           // t-chunk
    const int b  = blockIdx.y;           // batch

    float Ak[Kn], Bk[Kn], Gk[Kn];
#pragma unroll
    for (int k = 0; k < Kn; ++k) {
        Ak[k] = CA[k * Dn + d];
        Bk[k] = CB[k * Dn + d];
        Gk[k] = CG[k * Dn + d];
    }

    float s0[Kn], s1[Kn], s3[Kn];
#pragma unroll
    for (int k = 0; k < Kn; ++k) { s0[k] = 0.f; s1[k] = 0.f; s3[k] = 0.f; }

    const float* xp = X + ((size_t)b * Tn + (size_t)tc * tch) * Dn + d;
#pragma unroll 4
    for (int t = 0; t < tch; ++t) {
        float x = xp[(size_t)t * Dn];
        float p[Kn];
        float sum = EPS;
#pragma unroll
        for (int k = 0; k < Kn; ++k) {
            float arg = fmaf(fmaf(Ak[k], x, Bk[k]), x, Gk[k]);
            p[k] = fexp2(arg);
            sum += p[k];
        }
        float inv = frcp(sum);
        float xx  = x * x;
#pragma unroll
        for (int k = 0; k < Kn; ++k) {
            float tau = p[k] * inv;
            s0[k] += tau;
            s1[k]  = fmaf(tau, x, s1[k]);
            float t3 = tau * tau * tau;
            s3[k]  = fmaf(t3, xx, s3[k]);
        }
    }

#pragma unroll
    for (int k = 0; k < Kn; ++k) {
        size_t o = (size_t)tc * KBD + ((size_t)(k * Bn + b) << 8) + d;
        P0[o] = s0[k];
        P1[o] = s1[k];
        P3[o] = s3[k];
    }
}

// Reduce over tc: S0/A1/A3[k,b,d] = sum_tc P*
__global__ __launch_bounds__(256) void ucb_reduce(
    const float* __restrict__ P0, const float* __restrict__ P1,
    const float* __restrict__ P3,
    float* __restrict__ S0, float* __restrict__ A1, float* __restrict__ A3,
    int ts1)
{
    size_t idx = (size_t)blockIdx.x * 256 + threadIdx.x;  // over KBD
    float a = 0.f, b = 0.f, c = 0.f;
#pragma unroll 4
    for (int tc = 0; tc < ts1; ++tc) {
        size_t o = (size_t)tc * KBD + idx;
        a += P0[o];
        b += P1[o];
        c += P3[o];
    }
    S0[idx] = a;
    A1[idx] = b;
    A3[idx] = c;
}

// Mid: per (k,b,d) -> R = rs/sqrt(V+eps), RE = R*E
__global__ __launch_bounds__(256) void ucb_mid(
    const float* __restrict__ S0, const float* __restrict__ A1,
    const float* __restrict__ A3,
    float* __restrict__ R, float* __restrict__ RE)
{
    int idx = blockIdx.x * 256 + threadIdx.x;  // over K*B*D, ordered (k,b,d)
    int k = idx >> 12;                          // / (Bn*Dn)
    int d = idx & (Dn - 1);

    float s = EPS;
#pragma unroll
    for (int b2 = 0; b2 < Bn; ++b2)
        s += S0[((size_t)k * Bn + b2) * Dn + d];
    float iS = 1.0f / s;

    const float rs = rsqrtf(1.0f + EPS);        // 1/sqrt(pri+eps), pri==1
    float a1 = A1[idx];
    float a3 = A3[idx];
    float E  = a1 * iS * (1.0f / Tn);
    float V  = a3 * iS * iS * iS * (1.0f / Tn);
    float r  = rs * rsqrtf(V + EPS);
    R[idx]  = r;
    RE[idx] = r * E;
}

// Pass 2: out = (1/(sum_p+eps)) * sum_k p_k * (Rk*x - REk)
__global__ __launch_bounds__(256) void ucb_pass2(
    const float* __restrict__ X,
    const float* __restrict__ CA, const float* __restrict__ CB,
    const float* __restrict__ CG,
    const float* __restrict__ R, const float* __restrict__ RE,
    float* __restrict__ Out)
{
    const int d  = threadIdx.x;
    const int tc = blockIdx.x;
    const int b  = blockIdx.y;

    float Ak[Kn], Bk[Kn], Gk[Kn], Rk[Kn], REk[Kn];
#pragma unroll
    for (int k = 0; k < Kn; ++k) {
        Ak[k] = CA[k * Dn + d];
        Bk[k] = CB[k * Dn + d];
        Gk[k] = CG[k * Dn + d];
        size_t idx = ((size_t)k * Bn + b) * Dn + d;
        Rk[k]  = R[idx];
        REk[k] = RE[idx];
    }

    const size_t base = ((size_t)b * Tn + (size_t)tc * TCH2) * Dn + d;
#pragma unroll 4
    for (int t = 0; t < TCH2; ++t) {
        float x = X[base + (size_t)t * Dn];
        float p[Kn];
        float sum = EPS;
#pragma unroll
        for (int k = 0; k < Kn; ++k) {
            float arg = fmaf(fmaf(Ak[k], x, Bk[k]), x, Gk[k]);
            p[k] = fexp2(arg);
            sum += p[k];
        }
        float inv = frcp(sum);
        float acc = 0.f;
#pragma unroll
        for (int k = 0; k < Kn; ++k) {
            acc = fmaf(p[k], fmaf(Rk[k], x, -REk[k]), acc);
        }
        Out[base + (size_t)t * Dn] = acc * inv;
    }
}

extern "C" void kernel_launch(void* const* d_in, const int* in_sizes, int n_in,
                              void* d_out, int out_size, void* d_ws, size_t ws_size,
                              hipStream_t stream)
{
    const float* x    = (const float*)d_in[0];
    const float* mean = (const float*)d_in[1];
    const float* var  = (const float*)d_in[2];
    // d_in[3] (prior): softmax over singleton axis == 1 -> compile-time rsqrt(1+eps)

    // Pick TS1 (t-chunks for pass1) to fit workspace: 3 partial arrays of
    // TS1*KBD floats + 3*KBD (S0,A1,A3) + 2*KBD (R,RE) + 3*KD (coefs).
    int ts1 = 64;
    while (ts1 > 4) {
        size_t need = (3 * (size_t)ts1 * KBD + 5 * KBD + 3 * KD) * sizeof(float);
        if (need <= ws_size) break;
        ts1 >>= 1;
    }
    const int tch1 = Tn / ts1;

    float* P0 = (float*)d_ws;
    float* P1 = P0 + (size_t)ts1 * KBD;
    float* P3 = P1 + (size_t)ts1 * KBD;
    float* S0 = P3 + (size_t)ts1 * KBD;
    float* A1 = S0 + KBD;
    float* A3 = A1 + KBD;
    float* R  = A3 + KBD;
    float* RE = R  + KBD;
    float* CA = RE + KBD;
    float* CB = CA + KD;
    float* CG = CB + KD;

    ucb_coef<<<dim3(KD / 256), dim3(256), 0, stream>>>(mean, var, CA, CB, CG);

    ucb_pass1<<<dim3(ts1, Bn), dim3(256), 0, stream>>>(x, CA, CB, CG, P0, P1, P3, tch1);

    ucb_reduce<<<dim3(KBD / 256), dim3(256), 0, stream>>>(P0, P1, P3, S0, A1, A3, ts1);

    ucb_mid<<<dim3(KBD / 256), dim3(256), 0, stream>>>(S0, A1, A3, R, RE);

    ucb_pass2<<<dim3(TS2, Bn), dim3(256), 0, stream>>>(x, CA, CB, CG, R, RE, (float*)d_out);
}

// Round 4
// 59.230 us; speedup vs baseline: 2.0983x; 1.0147x over previous
//
#include <hip/hip_runtime.h>

#define EPS 1e-3f
#define Bn 16
#define Tn 2048
#define Dn 256
#define Kn 8
#define TS2 128          // t-chunks per batch row for pass2
#define TCH2 (Tn / TS2)  // 16

#define KBD ((size_t)Kn * Bn * Dn)   // 32768
#define NG  4                         // tc reduction groups

__device__ __forceinline__ float fexp2(float x) {
#if __has_builtin(__builtin_amdgcn_exp2f)
    return __builtin_amdgcn_exp2f(x);
#else
    return exp2f(x);
#endif
}

__device__ __forceinline__ float frcp(float x) {
#if __has_builtin(__builtin_amdgcn_rcpf)
    return __builtin_amdgcn_rcpf(x);
#else
    return 1.0f / x;
#endif
}

// per-thread coef computation: exp(-0.5 (x-m)^2/(softplus(v)+eps)) = exp2(Ax^2+Bx+G)
__device__ __forceinline__ void load_coefs(
    const float* __restrict__ Mean, const float* __restrict__ Var, int d,
    float* Ak, float* Bk, float* Gk)
{
    const float L2E = 1.4426950408889634f;
#pragma unroll
    for (int k = 0; k < Kn; ++k) {
        float m  = Mean[k * Dn + d];
        float v  = Var[k * Dn + d];
        float sp = logf(1.0f + expf(v));          // softplus
        float c2 = -0.5f * L2E / (sp + EPS);
        Ak[k] = c2;
        Bk[k] = -2.0f * c2 * m;
        Gk[k] = c2 * m * m;
    }
}

// Pass 1: per-block partials (no atomics):
//   P0[tc,k,b,d]=sum_t tau ; P1=sum_t tau*x ; P3=sum_t tau^3*x^2
__global__ __launch_bounds__(256) void ucb_pass1(
    const float* __restrict__ X,
    const float* __restrict__ Mean, const float* __restrict__ Var,
    float* __restrict__ P0, float* __restrict__ P1, float* __restrict__ P3,
    int tch)
{
    const int d  = threadIdx.x;          // 0..255 (= Dn)
    const int tc = blockIdx.x;           // t-chunk
    const int b  = blockIdx.y;           // batch

    float Ak[Kn], Bk[Kn], Gk[Kn];
    load_coefs(Mean, Var, d, Ak, Bk, Gk);

    float s0[Kn], s1[Kn], s3[Kn];
#pragma unroll
    for (int k = 0; k < Kn; ++k) { s0[k] = 0.f; s1[k] = 0.f; s3[k] = 0.f; }

    const float* xp = X + ((size_t)b * Tn + (size_t)tc * tch) * Dn + d;
#pragma unroll 4
    for (int t = 0; t < tch; ++t) {
        float x = xp[(size_t)t * Dn];
        float p[Kn];
        float sum = EPS;
#pragma unroll
        for (int k = 0; k < Kn; ++k) {
            float arg = fmaf(fmaf(Ak[k], x, Bk[k]), x, Gk[k]);
            p[k] = fexp2(arg);
            sum += p[k];
        }
        float q    = frcp(sum);
        float xq   = x * q;
        float q2   = q * q;
        float xxq3 = (x * x) * (q2 * q);
#pragma unroll
        for (int k = 0; k < Kn; ++k) {
            float pk = p[k];
            float p2 = pk * pk;
            float p3 = p2 * pk;
            s0[k] = fmaf(pk, q,    s0[k]);
            s1[k] = fmaf(pk, xq,   s1[k]);
            s3[k] = fmaf(p3, xxq3, s3[k]);
        }
    }

#pragma unroll
    for (int k = 0; k < Kn; ++k) {
        size_t o = (size_t)tc * KBD + ((size_t)(k * Bn + b) << 8) + d;
        P0[o] = s0[k];
        P1[o] = s1[k];
        P3[o] = s3[k];
    }
}

// Reduce stage A: Q[arr, g, idx] = sum over tcs in group g of P[arr][tc][idx]
__global__ __launch_bounds__(256) void ucb_reduceA(
    const float* __restrict__ P, float* __restrict__ Q, int ts1)
{
    const size_t idx = (size_t)blockIdx.x * 256 + threadIdx.x;  // over KBD
    const int arr = blockIdx.y;      // 0..2
    const int g   = blockIdx.z;      // 0..NG-1
    const int per = ts1 / NG;

    const float* p = P + ((size_t)arr * ts1 + (size_t)g * per) * KBD + idx;
    float a = 0.f;
#pragma unroll 4
    for (int i = 0; i < per; ++i)
        a += p[(size_t)i * KBD];
    Q[((size_t)(arr * NG + g)) * KBD + idx] = a;
}

// Mid: per (k,b,d): S = eps + sum_{b2,g} Q0 ; A1/A3 = sum_g Q1/Q3 ; -> R, RE
__global__ __launch_bounds__(256) void ucb_mid(
    const float* __restrict__ Q,
    float* __restrict__ R, float* __restrict__ RE)
{
    const size_t idx = (size_t)blockIdx.x * 256 + threadIdx.x;  // over KBD
    const int k = (int)(idx >> 12);          // / (Bn*Dn)
    const int d = (int)(idx & (Dn - 1));

    float s = EPS;
#pragma unroll
    for (int g = 0; g < NG; ++g) {
        const float* q0 = Q + (size_t)g * KBD + ((size_t)k << 12) + d;
#pragma unroll
        for (int b2 = 0; b2 < Bn; ++b2)
            s += q0[(size_t)b2 << 8];
    }
    float iS = frcp(s);

    float a1 = 0.f, a3 = 0.f;
#pragma unroll
    for (int g = 0; g < NG; ++g) {
        a1 += Q[((size_t)(NG + g))     * KBD + idx];
        a3 += Q[((size_t)(2 * NG + g)) * KBD + idx];
    }

    const float rs = rsqrtf(1.0f + EPS);     // 1/sqrt(pri+eps), pri==1
    float E  = a1 * iS * (1.0f / Tn);
    float V  = a3 * iS * iS * iS * (1.0f / Tn);
    float r  = rs * rsqrtf(V + EPS);
    R[idx]  = r;
    RE[idx] = r * E;
}

// Pass 2: out = (1/(sum_p+eps)) * sum_k p_k * (Rk*x - REk)
__global__ __launch_bounds__(256) void ucb_pass2(
    const float* __restrict__ X,
    const float* __restrict__ Mean, const float* __restrict__ Var,
    const float* __restrict__ R, const float* __restrict__ RE,
    float* __restrict__ Out)
{
    const int d  = threadIdx.x;
    const int tc = blockIdx.x;
    const int b  = blockIdx.y;

    float Ak[Kn], Bk[Kn], Gk[Kn];
    load_coefs(Mean, Var, d, Ak, Bk, Gk);

    float Rk[Kn], REk[Kn];
#pragma unroll
    for (int k = 0; k < Kn; ++k) {
        size_t idx = ((size_t)k * Bn + b) * Dn + d;
        Rk[k]  = R[idx];
        REk[k] = RE[idx];
    }

    const size_t base = ((size_t)b * Tn + (size_t)tc * TCH2) * Dn + d;
#pragma unroll 4
    for (int t = 0; t < TCH2; ++t) {
        float x = X[base + (size_t)t * Dn];
        float p[Kn];
        float sum = EPS;
#pragma unroll
        for (int k = 0; k < Kn; ++k) {
            float arg = fmaf(fmaf(Ak[k], x, Bk[k]), x, Gk[k]);
            p[k] = fexp2(arg);
            sum += p[k];
        }
        float inv = frcp(sum);
        float acc = 0.f;
#pragma unroll
        for (int k = 0; k < Kn; ++k) {
            acc = fmaf(p[k], fmaf(Rk[k], x, -REk[k]), acc);
        }
        Out[base + (size_t)t * Dn] = acc * inv;
    }
}

extern "C" void kernel_launch(void* const* d_in, const int* in_sizes, int n_in,
                              void* d_out, int out_size, void* d_ws, size_t ws_size,
                              hipStream_t stream)
{
    const float* x    = (const float*)d_in[0];
    const float* mean = (const float*)d_in[1];
    const float* var  = (const float*)d_in[2];
    // d_in[3] (prior): softmax over singleton axis == 1 -> compile-time rsqrt(1+eps)

    // ws: P (3*ts1*KBD) + Q (3*NG*KBD) + R,RE (2*KBD)
    int ts1 = 64;
    while (ts1 > NG) {
        size_t need = (3 * (size_t)ts1 * KBD + 3 * NG * KBD + 2 * KBD) * sizeof(float);
        if (need <= ws_size) break;
        ts1 >>= 1;
    }
    const int tch1 = Tn / ts1;

    float* P0 = (float*)d_ws;
    float* P1 = P0 + (size_t)ts1 * KBD;
    float* P3 = P1 + (size_t)ts1 * KBD;
    float* Q  = P3 + (size_t)ts1 * KBD;     // 3*NG*KBD
    float* R  = Q  + 3 * NG * KBD;
    float* RE = R  + KBD;

    ucb_pass1<<<dim3(ts1, Bn), dim3(256), 0, stream>>>(x, mean, var, P0, P1, P3, tch1);

    ucb_reduceA<<<dim3(KBD / 256, 3, NG), dim3(256), 0, stream>>>(P0, Q, ts1);

    ucb_mid<<<dim3(KBD / 256), dim3(256), 0, stream>>>(Q, R, RE);

    ucb_pass2<<<dim3(TS2, Bn), dim3(256), 0, stream>>>(x, mean, var, R, RE, (float*)d_out);
}